// Round 1
// 147.701 us; speedup vs baseline: 1.0082x; 1.0082x over previous
//
#include <hip/hip_runtime.h>
#include <hip/hip_bf16.h>
#include <stdint.h>

#define B_DIM   4096
#define IN_DIM  512
#define OUT_DIM 512
#define M_DIM   16
#define K_DIM   (IN_DIM * M_DIM)     // 8192
#define MN      (B_DIM * OUT_DIM)    // 2097152

typedef unsigned short ushort_t;
typedef __attribute__((ext_vector_type(8))) __bf16 bf16x8;
typedef __attribute__((ext_vector_type(4))) float  f32x4;

__device__ __forceinline__ ushort_t f2bf(float f) {
  union { float f; uint32_t u; } v; v.f = f;
  uint32_t u = v.u + 0x7fffu + ((v.u >> 16) & 1u);   // RNE
  return (ushort_t)(u >> 16);
}

// ---------- phase 1 (fused): coeffs fp32->bf16 AND basis computation ----------
#define CONV_N4      (OUT_DIM * K_DIM / 4)     // 1048576 float4s
#define CONV_BLOCKS  (CONV_N4 / 256)           // 4096
#define BASIS_BLOCKS (B_DIM * IN_DIM / 256)    // 8192

__global__ __launch_bounds__(256) void prep_kernel(
    const float* __restrict__ coeffs, ushort_t* __restrict__ coefb,
    const float* __restrict__ x, const float* __restrict__ bc,
    ushort_t* __restrict__ basis) {
  const int blk = blockIdx.x;
  const int tid = threadIdx.x;
  if (blk < CONV_BLOCKS) {
    // coeffs [OUT][IN][M] fp32 -> bf16 (== B^T [N][K])
    int i = blk * 256 + tid;
    float4 v = ((const float4*)coeffs)[i];
    ushort4 o;
    o.x = f2bf(v.x); o.y = f2bf(v.y); o.z = f2bf(v.z); o.w = f2bf(v.w);
    ((ushort4*)coefb)[i] = o;
    return;
  }
  // basis bf16 [B_DIM][IN_DIM*M_DIM], K index = i*16+m
  int idx = (blk - CONV_BLOCKS) * 256 + tid;   // one (b,i) pair per thread
  float xv = x[idx];
  float x2 = xv * xv, x3 = x2 * xv, x4 = x2 * x2;
  const float LOG2E = 1.44269504088896340736f;
  const float LN2   = 0.69314718055994530942f;
  uint32_t w[8];
  #pragma unroll
  for (int m = 0; m < 16; ++m) {
    float b1 = bc[m*8+0], b2 = bc[m*8+1], b3 = bc[m*8+2], b4 = bc[m*8+3];
    float b5 = bc[m*8+4], b6 = bc[m*8+5], b7 = bc[m*8+6], b8 = bc[m*8+7];
    float e     = __builtin_amdgcn_exp2f(b3 * xv * LOG2E);
    float inner = e - 1.0f;                                   // inner > 0 always
    float p     = __builtin_amdgcn_exp2f(b4 * __builtin_amdgcn_logf(inner));
    float u     = LN2 * __builtin_amdgcn_logf(1.0f + p);      // log1p(powered)
    float vv    = LN2 * __builtin_amdgcn_logf(1.0f + b2 * u); // log(1 + b2*u)
    float y = b1 * vv + b5 * xv + b6 * x2 + b7 * x3 + b8 * x4;
    uint32_t h = (uint32_t)f2bf(y);
    if (m & 1) w[m >> 1] |= (h << 16); else w[m >> 1] = h;
  }
  uint4* dst = (uint4*)(basis + (size_t)idx * 16);   // 32B contiguous per thread
  dst[0] = make_uint4(w[0], w[1], w[2], w[3]);
  dst[1] = make_uint4(w[4], w[5], w[6], w[7]);
}

// ---------- phase 2: GEMM C[M][N] = A[M][K] * Bt[N][K]^T, split-K, dbuf prefetch ----------
#define BM 128
#define BN 128
#define BK 32
#define SPLITK 8
#define KC (K_DIM / SPLITK)   // 1024 per split
#define NITER (KC / BK)       // 32 K-steps

#define GLD16(g, l) \
  __builtin_amdgcn_global_load_lds((const __attribute__((address_space(1))) void*)(g), \
                                   (__attribute__((address_space(3))) void*)(l), 16, 0, 0)

template <int ATOMIC>
__global__ __launch_bounds__(256, 4) void gemm_kernel(
    const ushort_t* __restrict__ A,   // basis [B_DIM][K_DIM] bf16
    const ushort_t* __restrict__ Bt,  // coeffs [OUT_DIM][K_DIM] bf16
    float* __restrict__ P) {          // partials [SPLITK][B][OUT] or out [B][OUT]
  __shared__ __align__(16) ushort_t As[2][BM * BK];
  __shared__ __align__(16) ushort_t Bs[2][BN * BK];
  const int tid  = threadIdx.x;
  const int wave = tid >> 6;
  const int lane = tid & 63;
  const int bm = blockIdx.x, bn = blockIdx.y, ks = blockIdx.z;

  // staging: one global_load_lds(16B) covers 16 rows (4 lanes/row of 8 bf16).
  // LDS is written LINEARLY (wave-uniform base + lane*16B); the bank-conflict
  // swizzle is applied by permuting the GLOBAL source k-slot (rule #21):
  //   LDS (row, slot_l) holds global slot_g = slot_l ^ ((row>>1)&3)
  // For the staging lane: row_local = wave*16 + (lane>>2), so (row>>1)&3 == (lane>>3)&3.
  const int srow = wave * 16 + (lane >> 2);
  const int scol = (((lane & 3) ^ ((lane >> 3) & 3)) * 8);   // pre-swizzled source slot
  const ushort_t* Ag  = A  + (size_t)(bm * BM + srow) * K_DIM + (size_t)ks * KC + scol;
  const ushort_t* Bg  = Bt + (size_t)(bn * BN + srow) * K_DIM + (size_t)ks * KC + scol;
  const ushort_t* Ag2 = Ag + (size_t)64 * K_DIM;
  const ushort_t* Bg2 = Bg + (size_t)64 * K_DIM;
  const int lofs  = wave * 16 * BK;          // wave-uniform LDS element offset
  const int lofs2 = (wave * 16 + 64) * BK;

#define STAGE(b) do { \
    GLD16(Ag,  &As[b][lofs]);  GLD16(Ag2, &As[b][lofs2]); \
    GLD16(Bg,  &Bs[b][lofs]);  GLD16(Bg2, &Bs[b][lofs2]); \
    Ag += BK; Ag2 += BK; Bg += BK; Bg2 += BK; } while (0)

  // 2x2 wave grid; each wave computes 64x64 via 4x4 tiles of 16x16x32 MFMA
  const int wr = wave >> 1, wc = wave & 1;
  const int fm = lane & 15;          // A row / Bt row within 16-tile
  // fragment k-slot = lane>>4; read the swizzled LDS slot. Fragment row R has
  // (R>>1)&3 == (fm>>1)&3 == (lane>>1)&3, so:
  const int fkswz = (((lane >> 4) ^ ((lane >> 1) & 3)) << 3);  // element offset in row

  f32x4 acc[4][4] = {};

#define COMPUTE(b) do { \
    bf16x8 af[4], bfv[4]; \
    _Pragma("unroll") \
    for (int t = 0; t < 4; ++t) { \
      af[t]  = *(const bf16x8*)&As[b][(wr * 64 + t * 16 + fm) * BK + fkswz]; \
      bfv[t] = *(const bf16x8*)&Bs[b][(wc * 64 + t * 16 + fm) * BK + fkswz]; \
    } \
    _Pragma("unroll") \
    for (int mt = 0; mt < 4; ++mt) \
      _Pragma("unroll") \
      for (int nt = 0; nt < 4; ++nt) \
        acc[mt][nt] = __builtin_amdgcn_mfma_f32_16x16x32_bf16(af[mt], bfv[nt], acc[mt][nt], 0, 0, 0); \
  } while (0)

  // 2-phase prefetch: stage tile t+1 while computing tile t; the vmcnt drain at
  // the barrier now happens AFTER a full MFMA phase instead of right after issue.
  STAGE(0);                                   // tile 0
  for (int kt = 0; kt < NITER - 2; kt += 2) {
    __syncthreads();                          // buf0 staged; buf1 reads drained
    STAGE(1);                                 // tile kt+1
    COMPUTE(0);                               // tile kt
    __syncthreads();                          // buf1 staged; buf0 reads drained
    STAGE(0);                                 // tile kt+2
    COMPUTE(1);                               // tile kt+1
  }
  __syncthreads();
  STAGE(1);                                   // tile NITER-1
  COMPUTE(0);                                 // tile NITER-2
  __syncthreads();
  COMPUTE(1);                                 // tile NITER-1

  // epilogue: C/D layout col = lane&15, row = (lane>>4)*4 + reg
  const int colb = bn * BN + wc * 64 + fm;
  const int rowb = bm * BM + wr * 64 + (lane >> 4) * 4;
  float* out = P + (ATOMIC ? (size_t)0 : (size_t)ks * MN);
  #pragma unroll
  for (int mt = 0; mt < 4; ++mt) {
    #pragma unroll
    for (int nt = 0; nt < 4; ++nt) {
      #pragma unroll
      for (int j = 0; j < 4; ++j) {
        int row = rowb + mt * 16 + j;
        int col = colb + nt * 16;
        float vv = acc[mt][nt][j];
        if (ATOMIC) atomicAdd(out + (size_t)row * OUT_DIM + col, vv);
        else        out[(size_t)row * OUT_DIM + col] = vv;
      }
    }
  }
#undef STAGE
#undef COMPUTE
}

// ---------- phase 3: reduce split-K partials ----------
__global__ __launch_bounds__(256) void reduce_kernel(
    const float* __restrict__ P, float* __restrict__ out) {
  int i = blockIdx.x * 256 + threadIdx.x;   // MN/4 threads
  const float4* p = (const float4*)P;
  float4 r = p[i];
  #pragma unroll
  for (int s = 1; s < SPLITK; ++s) {
    float4 v = p[i + (size_t)s * (MN / 4)];
    r.x += v.x; r.y += v.y; r.z += v.z; r.w += v.w;
  }
  ((float4*)out)[i] = r;
}

extern "C" void kernel_launch(void* const* d_in, const int* in_sizes, int n_in,
                              void* d_out, int out_size, void* d_ws, size_t ws_size,
                              hipStream_t stream) {
  const float* x      = (const float*)d_in[0];   // [4096][512]
  const float* coeffs = (const float*)d_in[1];   // [512][512][16]
  const float* b_coef = (const float*)d_in[2];   // [16][8]
  float* out = (float*)d_out;
  char*  ws  = (char*)d_ws;

  const size_t BASIS_BYTES = (size_t)B_DIM * K_DIM * 2;     // 64 MiB
  const size_t COEF_BYTES  = (size_t)OUT_DIM * K_DIM * 2;   // 8 MiB
  ushort_t* basis = (ushort_t*)ws;
  ushort_t* coefb = (ushort_t*)(ws + BASIS_BYTES);
  float* partials = (float*)(ws + BASIS_BYTES + COEF_BYTES);
  const size_t FULL = BASIS_BYTES + COEF_BYTES + (size_t)SPLITK * MN * 4;
  const bool use_atomic = (ws_size < FULL);   // deterministic per-session branch

  prep_kernel<<<CONV_BLOCKS + BASIS_BLOCKS, 256, 0, stream>>>(
      coeffs, coefb, x, b_coef, basis);

  dim3 grid(B_DIM / BM, OUT_DIM / BN, SPLITK);   // 32 x 4 x 8 = 1024 blocks
  if (use_atomic) {
    hipMemsetAsync(d_out, 0, (size_t)MN * 4, stream);
    gemm_kernel<1><<<grid, 256, 0, stream>>>(basis, coefb, out);
  } else {
    gemm_kernel<0><<<grid, 256, 0, stream>>>(basis, coefb, partials);
    reduce_kernel<<<MN / 4 / 256, 256, 0, stream>>>(partials, out);
  }
}

// Round 2
// 142.886 us; speedup vs baseline: 1.0422x; 1.0337x over previous
//
#include <hip/hip_runtime.h>
#include <hip/hip_bf16.h>
#include <stdint.h>

#define B_DIM   4096
#define IN_DIM  512
#define OUT_DIM 512
#define M_DIM   16
#define K_DIM   (IN_DIM * M_DIM)     // 8192
#define MN      (B_DIM * OUT_DIM)    // 2097152

typedef unsigned short ushort_t;
typedef __attribute__((ext_vector_type(8))) __bf16 bf16x8;
typedef __attribute__((ext_vector_type(4))) float  f32x4;

__device__ __forceinline__ ushort_t f2bf(float f) {
  union { float f; uint32_t u; } v; v.f = f;
  uint32_t u = v.u + 0x7fffu + ((v.u >> 16) & 1u);   // RNE
  return (ushort_t)(u >> 16);
}

// force a wave-uniform float into an SGPR
__device__ __forceinline__ float rfl(float f) {
  union { float f; int i; } v; v.f = f;
  v.i = __builtin_amdgcn_readfirstlane(v.i);
  return v.f;
}

// ---------- phase 1: coeffs fp32 -> bf16 (layout [OUT][IN][M] == B^T [N][K]) ----------
#define CONV_N4 (OUT_DIM * K_DIM / 4)
__global__ __launch_bounds__(256) void convert_coeffs_kernel(
    const float* __restrict__ src, ushort_t* __restrict__ dst) {
  int i = blockIdx.x * 256 + threadIdx.x;
  float4 v = ((const float4*)src)[i];
  ushort4 o;
  o.x = f2bf(v.x); o.y = f2bf(v.y); o.z = f2bf(v.z); o.w = f2bf(v.w);
  ((ushort4*)dst)[i] = o;
}

// ---------- phase 2: FUSED basis+GEMM. C[M][N] = A[M][K]*Bt[N][K]^T ----------
// A (basis) is never materialized in HBM: each block computes its A-tile into LDS.
// BN = 512 = full N  =>  each basis value computed exactly once (no redundancy).
#define BM 128
#define BN 512
#define BK 32                 // = 2 input-columns x 16 m
#define SPLITK 8
#define KC (K_DIM / SPLITK)   // 1024
#define NITER (KC / BK)       // 32 K-steps

#define GLD16(g, l) \
  __builtin_amdgcn_global_load_lds((const __attribute__((address_space(1))) void*)(g), \
                                   (__attribute__((address_space(3))) void*)(l), 16, 0, 0)

template <int ATOMIC>
__global__ __launch_bounds__(512, 2) void gemm_kernel(
    const float* __restrict__ x,      // [B_DIM][IN_DIM] fp32
    const ushort_t* __restrict__ Bt,  // coeffs bf16 [OUT_DIM][K_DIM]
    const float* __restrict__ bc,     // [16][8]
    float* __restrict__ P) {          // partials [SPLITK][B][OUT] or out
  __shared__ __align__(16) ushort_t As[2][BM * BK];   // 2 x 8 KiB
  __shared__ __align__(16) ushort_t Bs[2][BN * BK];   // 2 x 32 KiB
  const int tid  = threadIdx.x;
  const int wave = tid >> 6;
  const int lane = tid & 63;
  // decode so all 32 blocks of one k-slice land on one XCD (B-slice L2-hot)
  const int wgid = blockIdx.x;
  const int ks = wgid & 7, bm = wgid >> 3;

  // ---- B staging: global_load_lds linear dest, pre-swizzled source slot ----
  // LDS[row][slot] holds global slot^((row>>1)&3); row_local = lane>>2 per instr.
  const int srow = wave * 16 + (lane >> 2);
  const int scol = (((lane & 3) ^ ((lane >> 3) & 3)) * 8);
  const ushort_t* Bg0 = Bt + (size_t)srow * K_DIM + ks * KC + scol;
  const ushort_t* Bg1 = Bg0 + (size_t)128 * K_DIM;
  const ushort_t* Bg2 = Bg0 + (size_t)256 * K_DIM;
  const ushort_t* Bg3 = Bg0 + (size_t)384 * K_DIM;
  const int bofs0 = (wave * 16) * BK;
  const int bofs1 = (128 + wave * 16) * BK;
  const int bofs2 = (256 + wave * 16) * BK;
  const int bofs3 = (384 + wave * 16) * BK;

#define STAGEB(b) do { \
    GLD16(Bg0, &Bs[b][bofs0]); GLD16(Bg1, &Bs[b][bofs1]); \
    GLD16(Bg2, &Bs[b][bofs2]); GLD16(Bg3, &Bs[b][bofs3]); \
    Bg0 += BK; Bg1 += BK; Bg2 += BK; Bg3 += BK; } while (0)

  // ---- basis production: thread -> (row, i_local, m-half). half is WAVE-uniform
  // so the 64 b-coefs for this wave's 8 m's live in SGPRs. ----
  const int half = wave & 1;                       // m in [half*8, half*8+8)
  const int arow = (wave >> 1) * 32 + (lane >> 1); // 0..127
  const int il   = lane & 1;                       // which of 2 input cols in BK
  // logical 16B slot = il*2+half; write XOR-swizzled (matches read swizzle)
  const int aslot = ((il * 2 + half) ^ ((lane >> 2) & 3));
  const int awe   = arow * BK + aslot * 8;
  const float* xq = x + (size_t)(bm * BM + arow) * IN_DIM + ks * (KC / M_DIM) + il;

  float c1[8], c2[8], c3[8], c4[8], c5[8], c6[8], c7[8], c8[8];
  {
    const float* bch = bc + half * 64;
    #pragma unroll
    for (int m = 0; m < 8; ++m) {
      c1[m] = rfl(bch[m*8+0]); c2[m] = rfl(bch[m*8+1]);
      c3[m] = rfl(bch[m*8+2]); c4[m] = rfl(bch[m*8+3]);
      c5[m] = rfl(bch[m*8+4]); c6[m] = rfl(bch[m*8+5]);
      c7[m] = rfl(bch[m*8+6]); c8[m] = rfl(bch[m*8+7]);
    }
  }

  const float LOG2E = 1.44269504088896340736f;
  const float LN2   = 0.69314718055994530942f;
#define BASIS(b, t) do { \
    float xv = xq[(t) * 2]; \
    float xl2 = xv * LOG2E; \
    float x2 = xv * xv, x3 = x2 * xv, x4 = x2 * x2; \
    uint32_t wd[4]; \
    _Pragma("unroll") \
    for (int mi = 0; mi < 8; ++mi) { \
      float e     = __builtin_amdgcn_exp2f(c3[mi] * xl2); \
      float inner = e - 1.0f; \
      float p     = __builtin_amdgcn_exp2f(c4[mi] * __builtin_amdgcn_logf(inner)); \
      float u     = LN2 * __builtin_amdgcn_logf(1.0f + p); \
      float vv    = LN2 * __builtin_amdgcn_logf(1.0f + c2[mi] * u); \
      float y = c1[mi] * vv + c5[mi] * xv + c6[mi] * x2 + c7[mi] * x3 + c8[mi] * x4; \
      uint32_t h = (uint32_t)f2bf(y); \
      if (mi & 1) wd[mi >> 1] |= (h << 16); else wd[mi >> 1] = h; \
    } \
    *(uint4*)&As[b][awe] = make_uint4(wd[0], wd[1], wd[2], wd[3]); \
  } while (0)

  // ---- MFMA geometry: 8 waves as 2x4 grid of 64x128 wave-tiles ----
  const int wr = wave >> 2, wc = wave & 3;
  const int fm = lane & 15;
  const int fkswz = (((lane >> 4) ^ ((lane >> 1) & 3)) << 3);

  f32x4 acc[4][8] = {};

#define COMPUTE(b) do { \
    bf16x8 af[4], bfv[8]; \
    _Pragma("unroll") \
    for (int t2 = 0; t2 < 4; ++t2) \
      af[t2] = *(const bf16x8*)&As[b][(wr * 64 + t2 * 16 + fm) * BK + fkswz]; \
    _Pragma("unroll") \
    for (int u = 0; u < 8; ++u) \
      bfv[u] = *(const bf16x8*)&Bs[b][(wc * 128 + u * 16 + fm) * BK + fkswz]; \
    _Pragma("unroll") \
    for (int mt = 0; mt < 4; ++mt) \
      _Pragma("unroll") \
      for (int nt = 0; nt < 8; ++nt) \
        acc[mt][nt] = __builtin_amdgcn_mfma_f32_16x16x32_bf16(af[mt], bfv[nt], acc[mt][nt], 0, 0, 0); \
  } while (0)

  // ---- 2-phase pipeline: stage/produce tile t+1 while computing tile t ----
  STAGEB(0); BASIS(0, 0);
  __syncthreads();
  for (int kt = 0; kt < NITER - 2; kt += 2) {
    STAGEB(1); COMPUTE(0); BASIS(1, kt + 1);
    __syncthreads();
    STAGEB(0); COMPUTE(1); BASIS(0, kt + 2);
    __syncthreads();
  }
  STAGEB(1); COMPUTE(0); BASIS(1, NITER - 1);
  __syncthreads();
  COMPUTE(1);

  // ---- epilogue: C/D layout col = lane&15, row = (lane>>4)*4 + reg ----
  const int colb = wc * 128 + fm;
  const int rowb = bm * BM + wr * 64 + (lane >> 4) * 4;
  float* out = P + (ATOMIC ? (size_t)0 : (size_t)ks * MN);
  #pragma unroll
  for (int mt = 0; mt < 4; ++mt) {
    #pragma unroll
    for (int nt = 0; nt < 8; ++nt) {
      #pragma unroll
      for (int j = 0; j < 4; ++j) {
        int row = rowb + mt * 16 + j;
        int col = colb + nt * 16;
        float vv = acc[mt][nt][j];
        if (ATOMIC) atomicAdd(out + (size_t)row * OUT_DIM + col, vv);
        else        out[(size_t)row * OUT_DIM + col] = vv;
      }
    }
  }
#undef STAGEB
#undef BASIS
#undef COMPUTE
}

// ---------- phase 3: reduce split-K partials ----------
__global__ __launch_bounds__(256) void reduce_kernel(
    const float* __restrict__ P, float* __restrict__ out) {
  int i = blockIdx.x * 256 + threadIdx.x;
  const float4* p = (const float4*)P;
  float4 r = p[i];
  #pragma unroll
  for (int s = 1; s < SPLITK; ++s) {
    float4 v = p[i + (size_t)s * (MN / 4)];
    r.x += v.x; r.y += v.y; r.z += v.z; r.w += v.w;
  }
  ((float4*)out)[i] = r;
}

extern "C" void kernel_launch(void* const* d_in, const int* in_sizes, int n_in,
                              void* d_out, int out_size, void* d_ws, size_t ws_size,
                              hipStream_t stream) {
  const float* x      = (const float*)d_in[0];   // [4096][512]
  const float* coeffs = (const float*)d_in[1];   // [512][512][16]
  const float* b_coef = (const float*)d_in[2];   // [16][8]
  float* out = (float*)d_out;
  char*  ws  = (char*)d_ws;

  const size_t COEF_BYTES = (size_t)OUT_DIM * K_DIM * 2;   // 8 MiB
  ushort_t* coefb = (ushort_t*)ws;
  float* partials = (float*)(ws + COEF_BYTES);
  const size_t FULL = COEF_BYTES + (size_t)SPLITK * MN * 4;  // 72 MiB
  const bool use_atomic = (ws_size < FULL);   // deterministic per-session branch

  convert_coeffs_kernel<<<CONV_N4 / 256, 256, 0, stream>>>(coeffs, coefb);

  const int nblk = (B_DIM / BM) * SPLITK;   // 32 x 8 = 256 blocks, 1/CU
  if (use_atomic) {
    hipMemsetAsync(d_out, 0, (size_t)MN * 4, stream);
    gemm_kernel<1><<<nblk, 512, 0, stream>>>(x, coefb, b_coef, out);
  } else {
    gemm_kernel<0><<<nblk, 512, 0, stream>>>(x, coefb, b_coef, partials);
    reduce_kernel<<<MN / 4 / 256, 256, 0, stream>>>(partials, out);
  }
}